// Round 16
// baseline (797.430 us; speedup 1.0000x reference)
//
#include <hip/hip_runtime.h>

#define B_  2
#define S_  2048
#define NH_ 32
#define HD_ 128
#define H_  4096
#define H3_ 12288
#define GP_ 8   // compute_g partial chunks

typedef __bf16 bf16x8 __attribute__((ext_vector_type(8)));
typedef float  f32x4  __attribute__((ext_vector_type(4)));
typedef float  f32x16 __attribute__((ext_vector_type(16)));

__device__ __forceinline__ unsigned short f2bf(float f) {
  unsigned int u = __float_as_uint(f);
  u += 0x7fffu + ((u >> 16) & 1u);
  return (unsigned short)(u >> 16);
}
__device__ __forceinline__ __bf16 u2bf(unsigned short u) {
  return *reinterpret_cast<__bf16*>(&u);
}
__device__ __forceinline__ void unpack8(uint4 r, float f[8]) {
  f[0] = __uint_as_float(r.x << 16); f[1] = __uint_as_float(r.x & 0xffff0000u);
  f[2] = __uint_as_float(r.y << 16); f[3] = __uint_as_float(r.y & 0xffff0000u);
  f[4] = __uint_as_float(r.z << 16); f[5] = __uint_as_float(r.z & 0xffff0000u);
  f[6] = __uint_as_float(r.w << 16); f[7] = __uint_as_float(r.w & 0xffff0000u);
}
__device__ __forceinline__ void gload_lds16(const void* g, void* l) {
  __builtin_amdgcn_global_load_lds(
      (const __attribute__((address_space(1))) unsigned int*)g,
      (__attribute__((address_space(3))) unsigned int*)l, 16, 0, 0);
}

// ---------------- fused f32 -> bf16 converts (one launch, 3 segments) --------
__device__ __forceinline__ void cvt_seg(const float* __restrict__ in,
                                        unsigned short* __restrict__ out,
                                        long n, long base, long stride) {
  for (long i = base; i < n; i += stride) {
    float4 v = *(const float4*)(in + i);
    ushort4 o;
    o.x = f2bf(v.x); o.y = f2bf(v.y); o.z = f2bf(v.z); o.w = f2bf(v.w);
    *(ushort4*)(out + i) = o;
  }
}
__global__ __launch_bounds__(256) void cvt3(
    const float* __restrict__ a, unsigned short* __restrict__ oa, long na,
    const float* __restrict__ b, unsigned short* __restrict__ ob, long nb,
    const float* __restrict__ c, unsigned short* __restrict__ oc, long nc) {
  const long base = ((long)blockIdx.x * 256 + threadIdx.x) * 4;
  const long stride = (long)gridDim.x * 256 * 4;
  cvt_seg(a, oa, na, base, stride);
  cvt_seg(b, ob, nb, base, stride);
  cvt_seg(c, oc, nc, base, stride);
}

// =============================================================================
// 256x256-tile bf16 GEMM — 16-wave / 2-stage variant: 64x64 wave tiles,
// 2-stage LDS double-buffer (64 KB) -> 2 blocks/CU -> 8 waves/SIMD
// (launch_bounds(1024,2); VGPR=56 from r15 permits it). Prefetch of tile t+1
// issued a full K-step before its vmcnt(0) drain; cross-block TLP hides the
// drain. Same chunk-XOR swizzle (0 conflicts), setprio around MFMA cluster.
// EPI 0: bf16 out + bias ; EPI 1: f32 out + bias + residual
// =============================================================================
template <int EPI>
__global__ __launch_bounds__(1024, 2) void gemm256(
    const unsigned short* __restrict__ A, const unsigned short* __restrict__ Bt,
    void* __restrict__ C, const float* __restrict__ bias, const float* __restrict__ Res,
    int lda, int ldb, int ldc, int K)
{
  __shared__ __align__(16) unsigned short lds[2 * 16384];   // 2 x (A 16KB + B 16KB)

  const int tid = threadIdx.x;
  const int w = tid >> 6, l = tid & 63;

  const int gx = gridDim.x;
  const int nwg = gx * gridDim.y;
  const int flat = blockIdx.y * gx + blockIdx.x;
  const int swz = (flat & 7) * (nwg >> 3) + (flat >> 3);
  const int m0 = (swz / gx) * 256;
  const int n0 = (swz % gx) * 256;

  const int wr = w >> 2, wc = w & 3;      // 4x4 wave grid; wave tile 64x64
  const int lr16 = l & 15, kq = l >> 4;

  // staging: thread covers row tid>>2 (0-255), physical chunk tid&3;
  // pre-swizzled source chunk = (tid&3) ^ ((tid>>3)&3)   [row bits 1..2]
  const int srow = tid >> 2;
  const int scs  = (((tid & 3) ^ ((tid >> 3) & 3)) << 3);
  const unsigned short* ga = A  + (long)(m0 + srow) * lda + scs;
  const unsigned short* gb = Bt + (long)(n0 + srow) * ldb + scs;
  unsigned short* sb_w = lds + w * 512;   // wave-uniform dest (tid*8 elems)

  // ds_read: logical chunk kq of frag-row rr at physical chunk kq^((rr>>1)&3)
  const int rchunk = ((kq ^ ((l >> 1) & 3)) << 3);

  const int NT = K >> 5;

  const f32x4 zero = {0.f, 0.f, 0.f, 0.f};
  f32x4 acc[4][4];
#pragma unroll
  for (int m = 0; m < 4; ++m)
#pragma unroll
    for (int n = 0; n < 4; ++n) acc[m][n] = zero;

  auto stage = [&](int kt, int s) {
    gload_lds16(ga + (long)kt * 32, sb_w + s * 16384);          // A half
    gload_lds16(gb + (long)kt * 32, sb_w + s * 16384 + 8192);   // B half
  };

  stage(0, 0);
  asm volatile("s_waitcnt vmcnt(0)" ::: "memory");
  __builtin_amdgcn_s_barrier();

  for (int t = 0; t < NT; ++t) {
    const int cur = t & 1;
    if (t + 1 < NT) stage(t + 1, cur ^ 1);   // prefetch issued a K-step early

    const unsigned short* sa = lds + cur * 16384;
    const unsigned short* sbB = sa + 8192;
    bf16x8 av[4], bv[4];
#pragma unroll
    for (int n = 0; n < 4; ++n)
      bv[n] = *(const bf16x8*)&sbB[(wc * 64 + n * 16 + lr16) * 32 + rchunk];
#pragma unroll
    for (int m = 0; m < 4; ++m)
      av[m] = *(const bf16x8*)&sa[(wr * 64 + m * 16 + lr16) * 32 + rchunk];

    __builtin_amdgcn_s_setprio(1);
#pragma unroll
    for (int m = 0; m < 4; ++m)
#pragma unroll
      for (int n = 0; n < 4; ++n)
        acc[m][n] = __builtin_amdgcn_mfma_f32_16x16x32_bf16(av[m], bv[n], acc[m][n], 0, 0, 0);
    __builtin_amdgcn_s_setprio(0);

    if (t + 1 < NT) {
      asm volatile("s_waitcnt vmcnt(0)" ::: "memory");   // tile t+1 resident
      __builtin_amdgcn_s_barrier();
    }
  }

  // epilogue: C/D layout col=lane&15, row=(lane>>4)*4+i
#pragma unroll
  for (int m = 0; m < 4; ++m) {
    const int grow0 = m0 + wr * 64 + m * 16 + kq * 4;
#pragma unroll
    for (int n = 0; n < 4; ++n) {
      const int gcol = n0 + wc * 64 + n * 16 + lr16;
#pragma unroll
      for (int i = 0; i < 4; ++i) {
        const long gi = (long)(grow0 + i) * ldc + gcol;
        float v = acc[m][n][i];
        if (EPI == 0) {
          ((unsigned short*)C)[gi] = f2bf(v + bias[gcol]);
        } else {
          ((float*)C)[gi] = v + bias[gcol] + Res[gi];
        }
      }
    }
  }
}

// ---------------- single-stage Z-GEMM: Z[b,s,n,:] = Ginv_{b,n} q_{b,n}(s) ----
__global__ __launch_bounds__(256) void zgemm(
    const unsigned short* __restrict__ fused, const unsigned short* __restrict__ Ginv,
    unsigned short* __restrict__ Zb)
{
  __shared__ __align__(16) unsigned short As[128 * 128];
  __shared__ __align__(16) unsigned short Bs[128 * 128];
  const int z = blockIdx.z;           // b*32+n
  const int zb = z >> 5, zn = z & 31;
  const int m0 = blockIdx.y * 128;
  const unsigned short* A  = fused + (long)zb * S_ * H3_ + zn * 384 + (long)m0 * H3_;
  const unsigned short* Bg = Ginv + (long)z * 16384;
  const int t = threadIdx.x;
  const int wave = t >> 6, l = t & 63;
  const int wr = wave >> 1, wc = wave & 1;
  const int lr = l & 15, kq = l >> 4;

  {
    const int pc = t & 15;
#pragma unroll
    for (int r = 0; r < 8; ++r) {
      const int row = (r * 256 + t) >> 4;
      const int sc = ((pc ^ (row & 7)) << 3);
      gload_lds16(A + (long)row * H3_ + sc, (char*)As + r * 4096 + wave * 1024);
      gload_lds16(Bg + row * 128 + sc,      (char*)Bs + r * 4096 + wave * 1024);
    }
  }
  asm volatile("s_waitcnt vmcnt(0)" ::: "memory");
  __syncthreads();

  const f32x4 zero = {0.f, 0.f, 0.f, 0.f};
  f32x4 acc[4][4];
#pragma unroll
  for (int m = 0; m < 4; ++m)
#pragma unroll
    for (int n = 0; n < 4; ++n) acc[m][n] = zero;

#pragma unroll
  for (int kk = 0; kk < 4; ++kk) {
    bf16x8 av[4], bv[4];
#pragma unroll
    for (int m = 0; m < 4; ++m) {
      const int row = wr * 64 + m * 16 + lr;
      av[m] = *(const bf16x8*)&As[row * 128 + (((kk * 4 + kq) ^ (row & 7)) << 3)];
    }
#pragma unroll
    for (int n = 0; n < 4; ++n) {
      const int row = wc * 64 + n * 16 + lr;
      bv[n] = *(const bf16x8*)&Bs[row * 128 + (((kk * 4 + kq) ^ (row & 7)) << 3)];
    }
#pragma unroll
    for (int m = 0; m < 4; ++m)
#pragma unroll
      for (int n = 0; n < 4; ++n)
        acc[m][n] = __builtin_amdgcn_mfma_f32_16x16x32_bf16(av[m], bv[n], acc[m][n], 0, 0, 0);
  }

#pragma unroll
  for (int m = 0; m < 4; ++m) {
    const int grow0 = wr * 64 + m * 16 + kq * 4;
#pragma unroll
    for (int n = 0; n < 4; ++n) {
      const int gcol = wc * 64 + n * 16 + lr;
#pragma unroll
      for (int r = 0; r < 4; ++r) {
        const long gi = ((long)zb * S_ + m0 + grow0 + r) * H_ + zn * HD_ + gcol;
        Zb[gi] = f2bf(acc[m][n][r]);
      }
    }
  }
}

// ---------------- G partials via MFMA: Gpart[z][p] = Q_chunk^T Q_chunk -------
__global__ __launch_bounds__(256) void compute_g(const unsigned short* __restrict__ fused,
                                                 float* __restrict__ Gpart)
{
  __shared__ __align__(16) unsigned short Qs[64 * 136];
  const int z = blockIdx.x;            // b*32+n
  const int b = z >> 5, n = z & 31;
  const unsigned short* Q = fused + (long)b * S_ * H3_ + n * 384;
  const int t = threadIdx.x;
  const int w = t >> 6, l = t & 63;
  const int l31 = l & 31, hi = l >> 5;
  const int ar0 = (w & 1) * 2, ac0 = (w >> 1) * 2;

  f32x16 acc[2][2];
#pragma unroll
  for (int i = 0; i < 2; ++i)
#pragma unroll
    for (int j = 0; j < 2; ++j)
#pragma unroll
      for (int r = 0; r < 16; ++r) acc[i][j][r] = 0.f;

  const int sbeg = blockIdx.y * (S_ / GP_);

  for (int ss0 = 0; ss0 < S_ / GP_; ss0 += 64) {
    __syncthreads();
#pragma unroll
    for (int pass = 0; pass < 4; ++pass) {
      const int sL = pass * 16 + (t >> 4);
      const int c = t & 15;
      uint4 v = *(const uint4*)(Q + (long)(sbeg + ss0 + sL) * H3_ + c * 8);
      *(uint4*)&Qs[sL * 136 + c * 8] = v;
    }
    __syncthreads();

#pragma unroll
    for (int ks = 0; ks < 4; ++ks) {
      const int sb = ks * 16 + hi * 8;
      bf16x8 fa[2], fb[2];
#pragma unroll
      for (int i = 0; i < 2; ++i) {
        const int colA = (ar0 + i) * 32 + l31;
        const int colB = (ac0 + i) * 32 + l31;
        bf16x8 ra, rbv;
#pragma unroll
        for (int j = 0; j < 8; ++j) {
          ra[j]  = u2bf(Qs[(sb + j) * 136 + colA]);
          rbv[j] = u2bf(Qs[(sb + j) * 136 + colB]);
        }
        fa[i] = ra; fb[i] = rbv;
      }
#pragma unroll
      for (int i = 0; i < 2; ++i)
#pragma unroll
        for (int j = 0; j < 2; ++j)
          acc[i][j] = __builtin_amdgcn_mfma_f32_32x32x16_bf16(fa[i], fb[j], acc[i][j], 0, 0, 0);
    }
  }

  float* Gp = Gpart + ((long)z * GP_ + blockIdx.y) * 16384;
#pragma unroll
  for (int i = 0; i < 2; ++i) {
    const int rowb = (ar0 + i) * 32 + 4 * hi;
#pragma unroll
    for (int j = 0; j < 2; ++j) {
      const int col = (ac0 + j) * 32 + l31;
#pragma unroll
      for (int r = 0; r < 16; ++r) {
        const int row = rowb + (r & 3) + 8 * (r >> 2);
        Gp[row * 128 + col] = acc[i][j][r];
      }
    }
  }
}

// ---------------- register-resident Gauss-Jordan inverse of SPD 128x128 ------
__global__ __launch_bounds__(1024) void invert_g(const float* __restrict__ Gpart,
                                                 unsigned short* __restrict__ Ginv)
{
  __shared__ __align__(16) float prow[2][128];
  __shared__ __align__(16) float pcol[2][128];
  const int z = blockIdx.x;
  const int t = threadIdx.x;
  const int c  = t & 127;
  const int rg = t >> 7;
  const float* Gz = Gpart + (long)z * GP_ * 16384;

  float a[16];
#pragma unroll
  for (int i = 0; i < 16; ++i) {
    const int idx = (rg * 16 + i) * 128 + c;
    float s = 0.f;
#pragma unroll
    for (int p = 0; p < GP_; ++p) s += Gz[p * 16384 + idx];
    a[i] = s;
  }

  for (int p = 0; p < 128; ++p) {
    const int buf = p & 1;
    const int prg = p >> 4, pi = p & 15;
    if (rg == prg) {
      float v = a[0];
#pragma unroll
      for (int i = 1; i < 16; ++i) v = (pi == i) ? a[i] : v;
      prow[buf][c] = v;
    }
    if (c == p) {
#pragma unroll
      for (int q = 0; q < 4; ++q) {
        float4 w4 = make_float4(a[q * 4], a[q * 4 + 1], a[q * 4 + 2], a[q * 4 + 3]);
        *(float4*)&pcol[buf][rg * 16 + q * 4] = w4;
      }
    }
    __syncthreads();
    const float invp = 1.0f / prow[buf][p];
    const float rowv = (c == p) ? invp : prow[buf][c] * invp;
#pragma unroll
    for (int q = 0; q < 4; ++q) {
      const float4 pc4 = *(const float4*)&pcol[buf][rg * 16 + q * 4];
      const float pcv[4] = {pc4.x, pc4.y, pc4.z, pc4.w};
#pragma unroll
      for (int j = 0; j < 4; ++j) {
        const int i = q * 4 + j;
        const int r = rg * 16 + i;
        const float cur = (c == p) ? 0.f : a[i];
        a[i] = (r == p) ? rowv : cur - pcv[j] * rowv;
      }
    }
  }
  unsigned short* Oz = Ginv + (long)z * 16384;
#pragma unroll
  for (int i = 0; i < 16; ++i) Oz[(rg * 16 + i) * 128 + c] = f2bf(a[i]);
}

// ---------------- per-position 32x32 head attention (MFMA grams + MFMA PV) ---
__global__ __launch_bounds__(256) void attn_pos(
    const unsigned short* __restrict__ fused, const unsigned short* __restrict__ Zb,
    const float* __restrict__ alibi, unsigned short* __restrict__ ctx)
{
  __shared__ __align__(16) unsigned short q_s[32 * 136];
  __shared__ __align__(16) unsigned short k_s[32 * 136];
  __shared__ __align__(16) unsigned short z_s[32 * 136];
  __shared__ __align__(16) unsigned short v_s[32 * 128];
  __shared__ float part[4][32][33];
  __shared__ unsigned short pbf[32 * 34];
  __shared__ float pden[NH_];
  __shared__ float alib[NH_];

  const int s = blockIdx.x, b = blockIdx.y;
  const int t = threadIdx.x;
  const int w = t >> 6, l = t & 63;
  const int l31 = l & 31, hi = l >> 5;
  const unsigned short* src = fused + ((long)b * S_ + s) * H3_;
  const unsigned short* zg = Zb + ((long)b * S_ + s) * H_;

  if (t < NH_) alib[t] = 0.08838834764831845f * alibi[((long)(b * NH_ + t)) * S_ + s];

  {
    const int i0 = t >> 4, c = t & 15;
    gload_lds16(src + i0 * 384 + 256 + c * 8,        (char*)v_s + w * 1024);
    gload_lds16(src + (i0 + 16) * 384 + 256 + c * 8, (char*)v_s + 4096 + w * 1024);
  }
  {
    const int row = t >> 3, c = (t & 7) * 16;
    uint4 a0 = *(const uint4*)(src + row * 384 + c);
    uint4 a1 = *(const uint4*)(src + row * 384 + c + 8);
    uint4 b0 = *(const uint4*)(src + row * 384 + 128 + c);
    uint4 b1 = *(const uint4*)(src + row * 384 + 128 + c + 8);
    uint4 c0 = *(const uint4*)(zg + row * 128 + c);
    uint4 c1 = *(const uint4*)(zg + row * 128 + c + 8);
    *(uint4*)&q_s[row * 136 + c] = a0; *(uint4*)&q_s[row * 136 + c + 8] = a1;
    *(uint4*)&k_s[row * 136 + c] = b0; *(uint4*)&k_s[row * 136 + c + 8] = b1;
    *(uint4*)&z_s[row * 136 + c] = c0; *(uint4*)&z_s[row * 136 + c + 8] = c1;
  }
  __syncthreads();

  // per-wave d-slice grams
  {
    f32x16 g1, g2;
#pragma unroll
    for (int r = 0; r < 16; ++r) { g1[r] = 0.f; g2[r] = 0.f; }
#pragma unroll
    for (int ks = 0; ks < 2; ++ks) {
      const int off = w * 32 + ks * 16 + hi * 8;
      bf16x8 aq = *(const bf16x8*)&q_s[l31 * 136 + off];
      bf16x8 bk = *(const bf16x8*)&k_s[l31 * 136 + off];
      bf16x8 bz = *(const bf16x8*)&z_s[l31 * 136 + off];
      g1 = __builtin_amdgcn_mfma_f32_32x32x16_bf16(aq, bk, g1, 0, 0, 0);
      g2 = __builtin_amdgcn_mfma_f32_32x32x16_bf16(aq, bz, g2, 0, 0, 0);
    }
    const float aj = alib[l31];
#pragma unroll
    for (int r = 0; r < 16; ++r) {
      const int row = (r & 3) + 8 * (r >> 2) + 4 * hi;
      part[w][row][l31] = 0.0078125f * g1[r] + aj * g2[r];
    }
  }
  __syncthreads();

  // wave-parallel softmax, reading the 4 wave-partials directly
  const int i = t >> 3;
  const int j0 = (t & 7) * 4;
  float wv[4];
#pragma unroll
  for (int jj = 0; jj < 4; ++jj)
    wv[jj] = part[0][i][j0 + jj] + part[1][i][j0 + jj]
           + part[2][i][j0 + jj] + part[3][i][j0 + jj];
  float vmax = fmaxf(fmaxf(wv[0], wv[1]), fmaxf(wv[2], wv[3]));
  vmax = fmaxf(vmax, __shfl_xor(vmax, 1));
  vmax = fmaxf(vmax, __shfl_xor(vmax, 2));
  vmax = fmaxf(vmax, __shfl_xor(vmax, 4));
  float ssum = 0.f;
#pragma unroll
  for (int jj = 0; jj < 4; ++jj) { wv[jj] = __expf(wv[jj] - vmax); ssum += wv[jj]; }
#pragma unroll
  for (int jj = 0; jj < 4; ++jj) pbf[i * 34 + j0 + jj] = f2bf(wv[jj]);
  ssum += __shfl_xor(ssum, 1);
  ssum += __shfl_xor(ssum, 2);
  ssum += __shfl_xor(ssum, 4);
  if ((t & 7) == 0) pden[i] = 1.0f / (ssum + 1e-8f);
  __syncthreads();

  // PV via MFMA: wave w -> d-slice w*32..w*32+31
  {
    f32x16 cacc;
#pragma unroll
    for (int r = 0; r < 16; ++r) cacc[r] = 0.f;
    bf16x8 pa[2], vb[2];
#pragma unroll
    for (int ks = 0; ks < 2; ++ks) {
      bf16x8 p8, v8;
#pragma unroll
      for (int jj = 0; jj < 8; ++jj) {
        const int k = ks * 16 + hi * 8 + jj;
        p8[jj] = u2bf(pbf[l31 * 34 + k]);
        v8[jj] = u2bf(v_s[k * 128 + w * 32 + l31]);
      }
      pa[ks] = p8; vb[ks] = v8;
    }
    cacc = __builtin_amdgcn_mfma_f32_32x32x16_bf16(pa[0], vb[0], cacc, 0, 0, 0);
    cacc = __builtin_amdgcn_mfma_f32_32x32x16_bf16(pa[1], vb[1], cacc, 0, 0, 0);

    unsigned short* cb = ctx + ((long)b * S_ + s) * H_ + w * 32 + l31;
#pragma unroll
    for (int r = 0; r < 16; ++r) {
      const int row = (r & 3) + 8 * (r >> 2) + 4 * hi;
      cb[row * HD_] = f2bf(cacc[r] * pden[row]);
    }
  }
}

// -----------------------------------------------------------------------------
extern "C" void kernel_launch(void* const* d_in, const int* in_sizes, int n_in,
                              void* d_out, int out_size, void* d_ws, size_t ws_size,
                              hipStream_t stream)
{
  (void)in_sizes; (void)n_in; (void)out_size; (void)ws_size;
  const float* hidden   = (const float*)d_in[0];
  const float* residual = (const float*)d_in[1];
  const float* alibi    = (const float*)d_in[2];
  const float* Wqkv     = (const float*)d_in[4];
  const float* bqkv     = (const float*)d_in[5];
  const float* Wd       = (const float*)d_in[6];
  const float* bd       = (const float*)d_in[7];
  float* out = (float*)d_out;

  char* ws = (char*)d_ws;
  size_t off = 0;
  auto carve = [&](size_t bytes) -> void* {
    void* p = ws + off;
    off += (bytes + 255) & ~(size_t)255;
    return p;
  };
  const long nHid = (long)B_ * S_ * H_;
  const long nWq  = (long)H3_ * H_;
  unsigned short* hid_bf   = (unsigned short*)carve((size_t)nHid * 2);
  unsigned short* wqkv_bf  = (unsigned short*)carve((size_t)nWq * 2);
  unsigned short* wd_bf    = (unsigned short*)carve((size_t)H_ * H_ * 2);
  unsigned short* fused_bf = (unsigned short*)carve((size_t)B_ * S_ * H3_ * 2);
  unsigned short* z_bf     = (unsigned short*)carve((size_t)nHid * 2);
  unsigned short* ctx_bf   = (unsigned short*)carve((size_t)nHid * 2);
  float*          Gpart    = (float*)carve((size_t)64 * GP_ * 16384 * 4);
  unsigned short* ginv_bf  = (unsigned short*)carve((size_t)64 * 16384 * 2);

  // 1) bf16 casts (single launch, 3 segments)
  cvt3<<<2048, 256, 0, stream>>>(hidden, hid_bf, nHid,
                                 Wqkv, wqkv_bf, nWq,
                                 Wd, wd_bf, (long)H_ * H_);

  // 2) fused = hidden @ Wqkv^T + b_qkv  (bf16 out)
  gemm256<0><<<dim3(H3_ / 256, (B_ * S_) / 256, 1), 1024, 0, stream>>>(
      hid_bf, wqkv_bf, fused_bf, bqkv, nullptr, H_, H_, H3_, H_);

  // 3) G partials via MFMA -> Ginv via register Gauss-Jordan (sums partials)
  compute_g<<<dim3(64, GP_), 256, 0, stream>>>(fused_bf, Gpart);
  invert_g<<<64, 1024, 0, stream>>>(Gpart, ginv_bf);

  // 4) Z[b,s,n,:] = Ginv_{b,n} q_{b,n}(s)  (single-stage batched GEMM)
  zgemm<<<dim3(1, S_ / 128, 64), 256, 0, stream>>>(fused_bf, ginv_bf, z_bf);

  // 5) per-position 32x32 head attention -> ctx (bf16)
  attn_pos<<<dim3(S_, B_), 256, 0, stream>>>(fused_bf, z_bf, alibi, ctx_bf);

  // 6) out = ctx @ Wd^T + b_dense + residual  (f32 out)
  gemm256<1><<<dim3(H_ / 256, (B_ * S_) / 256, 1), 1024, 0, stream>>>(
      ctx_bf, wd_bf, out, bd, residual, H_, H_, H_, H_);
}

// Round 17
// 743.022 us; speedup vs baseline: 1.0732x; 1.0732x over previous
//
#include <hip/hip_runtime.h>

#define B_  2
#define S_  2048
#define NH_ 32
#define HD_ 128
#define H_  4096
#define H3_ 12288
#define GP_ 8   // compute_g partial chunks

typedef __bf16 bf16x8 __attribute__((ext_vector_type(8)));
typedef float  f32x4  __attribute__((ext_vector_type(4)));
typedef float  f32x16 __attribute__((ext_vector_type(16)));

__device__ __forceinline__ unsigned short f2bf(float f) {
  unsigned int u = __float_as_uint(f);
  u += 0x7fffu + ((u >> 16) & 1u);
  return (unsigned short)(u >> 16);
}
__device__ __forceinline__ __bf16 u2bf(unsigned short u) {
  return *reinterpret_cast<__bf16*>(&u);
}
__device__ __forceinline__ void unpack8(uint4 r, float f[8]) {
  f[0] = __uint_as_float(r.x << 16); f[1] = __uint_as_float(r.x & 0xffff0000u);
  f[2] = __uint_as_float(r.y << 16); f[3] = __uint_as_float(r.y & 0xffff0000u);
  f[4] = __uint_as_float(r.z << 16); f[5] = __uint_as_float(r.z & 0xffff0000u);
  f[6] = __uint_as_float(r.w << 16); f[7] = __uint_as_float(r.w & 0xffff0000u);
}
__device__ __forceinline__ void gload_lds16(const void* g, void* l) {
  __builtin_amdgcn_global_load_lds(
      (const __attribute__((address_space(1))) unsigned int*)g,
      (__attribute__((address_space(3))) unsigned int*)l, 16, 0, 0);
}

// ---------------- fused f32 -> bf16 converts (one launch, 3 segments) --------
__device__ __forceinline__ void cvt_seg(const float* __restrict__ in,
                                        unsigned short* __restrict__ out,
                                        long n, long base, long stride) {
  for (long i = base; i < n; i += stride) {
    float4 v = *(const float4*)(in + i);
    ushort4 o;
    o.x = f2bf(v.x); o.y = f2bf(v.y); o.z = f2bf(v.z); o.w = f2bf(v.w);
    *(ushort4*)(out + i) = o;
  }
}
__global__ __launch_bounds__(256) void cvt3(
    const float* __restrict__ a, unsigned short* __restrict__ oa, long na,
    const float* __restrict__ b, unsigned short* __restrict__ ob, long nb,
    const float* __restrict__ c, unsigned short* __restrict__ oc, long nc) {
  const long base = ((long)blockIdx.x * 256 + threadIdx.x) * 4;
  const long stride = (long)gridDim.x * 256 * 4;
  cvt_seg(a, oa, na, base, stride);
  cvt_seg(b, ob, nb, base, stride);
  cvt_seg(c, oc, nc, base, stride);
}

// =============================================================================
// 256x256-tile bf16 GEMM — round-15 best-measured config: 16 waves (4x4 grid,
// 64x64 wave tiles), 3-stage LDS pipeline (96 KB), counted vmcnt(2) (one tile
// always in flight across the barrier), chunk-XOR swizzle (0 conflicts),
// setprio around the MFMA cluster, __launch_bounds__(1024,4) -> VGPR=56,
// 4 waves/SIMD so LDS-read bursts overlap MFMA bursts across waves.
// EPI 0: bf16 out + bias ; EPI 1: f32 out + bias + residual
// =============================================================================
template <int EPI>
__global__ __launch_bounds__(1024, 4) void gemm256(
    const unsigned short* __restrict__ A, const unsigned short* __restrict__ Bt,
    void* __restrict__ C, const float* __restrict__ bias, const float* __restrict__ Res,
    int lda, int ldb, int ldc, int K)
{
  __shared__ __align__(16) unsigned short lds[3 * 16384];   // 3 x (A 16KB + B 16KB)

  const int tid = threadIdx.x;
  const int w = tid >> 6, l = tid & 63;

  const int gx = gridDim.x;
  const int nwg = gx * gridDim.y;
  const int flat = blockIdx.y * gx + blockIdx.x;
  const int swz = (flat & 7) * (nwg >> 3) + (flat >> 3);
  const int m0 = (swz / gx) * 256;
  const int n0 = (swz % gx) * 256;

  const int wr = w >> 2, wc = w & 3;      // 4x4 wave grid; wave tile 64x64
  const int lr16 = l & 15, kq = l >> 4;

  // staging: thread covers row tid>>2 (0-255), physical chunk tid&3;
  // pre-swizzled source chunk = (tid&3) ^ ((tid>>3)&3)   [row bits 1..2]
  const int srow = tid >> 2;
  const int scs  = (((tid & 3) ^ ((tid >> 3) & 3)) << 3);
  const unsigned short* ga = A  + (long)(m0 + srow) * lda + scs;
  const unsigned short* gb = Bt + (long)(n0 + srow) * ldb + scs;
  unsigned short* sb_w = lds + w * 512;   // wave-uniform dest (tid*8 elems)

  // ds_read: logical chunk kq of frag-row rr at physical chunk kq^((rr>>1)&3)
  const int rchunk = ((kq ^ ((l >> 1) & 3)) << 3);

  const int NT = K >> 5;

  const f32x4 zero = {0.f, 0.f, 0.f, 0.f};
  f32x4 acc[4][4];
#pragma unroll
  for (int m = 0; m < 4; ++m)
#pragma unroll
    for (int n = 0; n < 4; ++n) acc[m][n] = zero;

  auto stage = [&](int kt, int s) {
    gload_lds16(ga + (long)kt * 32, sb_w + s * 16384);          // A half
    gload_lds16(gb + (long)kt * 32, sb_w + s * 16384 + 8192);   // B half
  };

  stage(0, 0);
  stage(1, 1);
  asm volatile("s_waitcnt vmcnt(2)" ::: "memory");
  __builtin_amdgcn_s_barrier();

  for (int t = 0; t < NT; ++t) {
    const int cur = t % 3;
    if (t + 2 < NT) stage(t + 2, (t + 2) % 3);

    const unsigned short* sa = lds + cur * 16384;
    const unsigned short* sbB = sa + 8192;
    bf16x8 av[4], bv[4];
#pragma unroll
    for (int n = 0; n < 4; ++n)
      bv[n] = *(const bf16x8*)&sbB[(wc * 64 + n * 16 + lr16) * 32 + rchunk];
#pragma unroll
    for (int m = 0; m < 4; ++m)
      av[m] = *(const bf16x8*)&sa[(wr * 64 + m * 16 + lr16) * 32 + rchunk];

    __builtin_amdgcn_s_setprio(1);
#pragma unroll
    for (int m = 0; m < 4; ++m)
#pragma unroll
      for (int n = 0; n < 4; ++n)
        acc[m][n] = __builtin_amdgcn_mfma_f32_16x16x32_bf16(av[m], bv[n], acc[m][n], 0, 0, 0);
    __builtin_amdgcn_s_setprio(0);

    if (t + 1 < NT) {
      if (t + 2 < NT) asm volatile("s_waitcnt vmcnt(2)" ::: "memory");
      else            asm volatile("s_waitcnt vmcnt(0)" ::: "memory");
      __builtin_amdgcn_s_barrier();
    }
  }

  // epilogue: C/D layout col=lane&15, row=(lane>>4)*4+i
#pragma unroll
  for (int m = 0; m < 4; ++m) {
    const int grow0 = m0 + wr * 64 + m * 16 + kq * 4;
#pragma unroll
    for (int n = 0; n < 4; ++n) {
      const int gcol = n0 + wc * 64 + n * 16 + lr16;
#pragma unroll
      for (int i = 0; i < 4; ++i) {
        const long gi = (long)(grow0 + i) * ldc + gcol;
        float v = acc[m][n][i];
        if (EPI == 0) {
          ((unsigned short*)C)[gi] = f2bf(v + bias[gcol]);
        } else {
          ((float*)C)[gi] = v + bias[gcol] + Res[gi];
        }
      }
    }
  }
}

// ---------------- single-stage Z-GEMM: Z[b,s,n,:] = Ginv_{b,n} q_{b,n}(s) ----
__global__ __launch_bounds__(256) void zgemm(
    const unsigned short* __restrict__ fused, const unsigned short* __restrict__ Ginv,
    unsigned short* __restrict__ Zb)
{
  __shared__ __align__(16) unsigned short As[128 * 128];
  __shared__ __align__(16) unsigned short Bs[128 * 128];
  const int z = blockIdx.z;           // b*32+n
  const int zb = z >> 5, zn = z & 31;
  const int m0 = blockIdx.y * 128;
  const unsigned short* A  = fused + (long)zb * S_ * H3_ + zn * 384 + (long)m0 * H3_;
  const unsigned short* Bg = Ginv + (long)z * 16384;
  const int t = threadIdx.x;
  const int wave = t >> 6, l = t & 63;
  const int wr = wave >> 1, wc = wave & 1;
  const int lr = l & 15, kq = l >> 4;

  {
    const int pc = t & 15;
#pragma unroll
    for (int r = 0; r < 8; ++r) {
      const int row = (r * 256 + t) >> 4;
      const int sc = ((pc ^ (row & 7)) << 3);
      gload_lds16(A + (long)row * H3_ + sc, (char*)As + r * 4096 + wave * 1024);
      gload_lds16(Bg + row * 128 + sc,      (char*)Bs + r * 4096 + wave * 1024);
    }
  }
  asm volatile("s_waitcnt vmcnt(0)" ::: "memory");
  __syncthreads();

  const f32x4 zero = {0.f, 0.f, 0.f, 0.f};
  f32x4 acc[4][4];
#pragma unroll
  for (int m = 0; m < 4; ++m)
#pragma unroll
    for (int n = 0; n < 4; ++n) acc[m][n] = zero;

#pragma unroll
  for (int kk = 0; kk < 4; ++kk) {
    bf16x8 av[4], bv[4];
#pragma unroll
    for (int m = 0; m < 4; ++m) {
      const int row = wr * 64 + m * 16 + lr;
      av[m] = *(const bf16x8*)&As[row * 128 + (((kk * 4 + kq) ^ (row & 7)) << 3)];
    }
#pragma unroll
    for (int n = 0; n < 4; ++n) {
      const int row = wc * 64 + n * 16 + lr;
      bv[n] = *(const bf16x8*)&Bs[row * 128 + (((kk * 4 + kq) ^ (row & 7)) << 3)];
    }
#pragma unroll
    for (int m = 0; m < 4; ++m)
#pragma unroll
      for (int n = 0; n < 4; ++n)
        acc[m][n] = __builtin_amdgcn_mfma_f32_16x16x32_bf16(av[m], bv[n], acc[m][n], 0, 0, 0);
  }

#pragma unroll
  for (int m = 0; m < 4; ++m) {
    const int grow0 = wr * 64 + m * 16 + kq * 4;
#pragma unroll
    for (int n = 0; n < 4; ++n) {
      const int gcol = wc * 64 + n * 16 + lr;
#pragma unroll
      for (int r = 0; r < 4; ++r) {
        const long gi = ((long)zb * S_ + m0 + grow0 + r) * H_ + zn * HD_ + gcol;
        Zb[gi] = f2bf(acc[m][n][r]);
      }
    }
  }
}

// ---------------- G partials via MFMA: Gpart[z][p] = Q_chunk^T Q_chunk -------
__global__ __launch_bounds__(256) void compute_g(const unsigned short* __restrict__ fused,
                                                 float* __restrict__ Gpart)
{
  __shared__ __align__(16) unsigned short Qs[64 * 136];
  const int z = blockIdx.x;            // b*32+n
  const int b = z >> 5, n = z & 31;
  const unsigned short* Q = fused + (long)b * S_ * H3_ + n * 384;
  const int t = threadIdx.x;
  const int w = t >> 6, l = t & 63;
  const int l31 = l & 31, hi = l >> 5;
  const int ar0 = (w & 1) * 2, ac0 = (w >> 1) * 2;

  f32x16 acc[2][2];
#pragma unroll
  for (int i = 0; i < 2; ++i)
#pragma unroll
    for (int j = 0; j < 2; ++j)
#pragma unroll
      for (int r = 0; r < 16; ++r) acc[i][j][r] = 0.f;

  const int sbeg = blockIdx.y * (S_ / GP_);

  for (int ss0 = 0; ss0 < S_ / GP_; ss0 += 64) {
    __syncthreads();
#pragma unroll
    for (int pass = 0; pass < 4; ++pass) {
      const int sL = pass * 16 + (t >> 4);
      const int c = t & 15;
      uint4 v = *(const uint4*)(Q + (long)(sbeg + ss0 + sL) * H3_ + c * 8);
      *(uint4*)&Qs[sL * 136 + c * 8] = v;
    }
    __syncthreads();

#pragma unroll
    for (int ks = 0; ks < 4; ++ks) {
      const int sb = ks * 16 + hi * 8;
      bf16x8 fa[2], fb[2];
#pragma unroll
      for (int i = 0; i < 2; ++i) {
        const int colA = (ar0 + i) * 32 + l31;
        const int colB = (ac0 + i) * 32 + l31;
        bf16x8 ra, rbv;
#pragma unroll
        for (int j = 0; j < 8; ++j) {
          ra[j]  = u2bf(Qs[(sb + j) * 136 + colA]);
          rbv[j] = u2bf(Qs[(sb + j) * 136 + colB]);
        }
        fa[i] = ra; fb[i] = rbv;
      }
#pragma unroll
      for (int i = 0; i < 2; ++i)
#pragma unroll
        for (int j = 0; j < 2; ++j)
          acc[i][j] = __builtin_amdgcn_mfma_f32_32x32x16_bf16(fa[i], fb[j], acc[i][j], 0, 0, 0);
    }
  }

  float* Gp = Gpart + ((long)z * GP_ + blockIdx.y) * 16384;
#pragma unroll
  for (int i = 0; i < 2; ++i) {
    const int rowb = (ar0 + i) * 32 + 4 * hi;
#pragma unroll
    for (int j = 0; j < 2; ++j) {
      const int col = (ac0 + j) * 32 + l31;
#pragma unroll
      for (int r = 0; r < 16; ++r) {
        const int row = rowb + (r & 3) + 8 * (r >> 2);
        Gp[row * 128 + col] = acc[i][j][r];
      }
    }
  }
}

// ---------------- register-resident Gauss-Jordan inverse of SPD 128x128 ------
__global__ __launch_bounds__(1024) void invert_g(const float* __restrict__ Gpart,
                                                 unsigned short* __restrict__ Ginv)
{
  __shared__ __align__(16) float prow[2][128];
  __shared__ __align__(16) float pcol[2][128];
  const int z = blockIdx.x;
  const int t = threadIdx.x;
  const int c  = t & 127;
  const int rg = t >> 7;
  const float* Gz = Gpart + (long)z * GP_ * 16384;

  float a[16];
#pragma unroll
  for (int i = 0; i < 16; ++i) {
    const int idx = (rg * 16 + i) * 128 + c;
    float s = 0.f;
#pragma unroll
    for (int p = 0; p < GP_; ++p) s += Gz[p * 16384 + idx];
    a[i] = s;
  }

  for (int p = 0; p < 128; ++p) {
    const int buf = p & 1;
    const int prg = p >> 4, pi = p & 15;
    if (rg == prg) {
      float v = a[0];
#pragma unroll
      for (int i = 1; i < 16; ++i) v = (pi == i) ? a[i] : v;
      prow[buf][c] = v;
    }
    if (c == p) {
#pragma unroll
      for (int q = 0; q < 4; ++q) {
        float4 w4 = make_float4(a[q * 4], a[q * 4 + 1], a[q * 4 + 2], a[q * 4 + 3]);
        *(float4*)&pcol[buf][rg * 16 + q * 4] = w4;
      }
    }
    __syncthreads();
    const float invp = 1.0f / prow[buf][p];
    const float rowv = (c == p) ? invp : prow[buf][c] * invp;
#pragma unroll
    for (int q = 0; q < 4; ++q) {
      const float4 pc4 = *(const float4*)&pcol[buf][rg * 16 + q * 4];
      const float pcv[4] = {pc4.x, pc4.y, pc4.z, pc4.w};
#pragma unroll
      for (int j = 0; j < 4; ++j) {
        const int i = q * 4 + j;
        const int r = rg * 16 + i;
        const float cur = (c == p) ? 0.f : a[i];
        a[i] = (r == p) ? rowv : cur - pcv[j] * rowv;
      }
    }
  }
  unsigned short* Oz = Ginv + (long)z * 16384;
#pragma unroll
  for (int i = 0; i < 16; ++i) Oz[(rg * 16 + i) * 128 + c] = f2bf(a[i]);
}

// ---------------- per-position 32x32 head attention (MFMA grams + MFMA PV) ---
__global__ __launch_bounds__(256) void attn_pos(
    const unsigned short* __restrict__ fused, const unsigned short* __restrict__ Zb,
    const float* __restrict__ alibi, unsigned short* __restrict__ ctx)
{
  __shared__ __align__(16) unsigned short q_s[32 * 136];
  __shared__ __align__(16) unsigned short k_s[32 * 136];
  __shared__ __align__(16) unsigned short z_s[32 * 136];
  __shared__ __align__(16) unsigned short v_s[32 * 128];
  __shared__ float part[4][32][33];
  __shared__ unsigned short pbf[32 * 34];
  __shared__ float pden[NH_];
  __shared__ float alib[NH_];

  const int s = blockIdx.x, b = blockIdx.y;
  const int t = threadIdx.x;
  const int w = t >> 6, l = t & 63;
  const int l31 = l & 31, hi = l >> 5;
  const unsigned short* src = fused + ((long)b * S_ + s) * H3_;
  const unsigned short* zg = Zb + ((long)b * S_ + s) * H_;

  if (t < NH_) alib[t] = 0.08838834764831845f * alibi[((long)(b * NH_ + t)) * S_ + s];

  {
    const int i0 = t >> 4, c = t & 15;
    gload_lds16(src + i0 * 384 + 256 + c * 8,        (char*)v_s + w * 1024);
    gload_lds16(src + (i0 + 16) * 384 + 256 + c * 8, (char*)v_s + 4096 + w * 1024);
  }
  {
    const int row = t >> 3, c = (t & 7) * 16;
    uint4 a0 = *(const uint4*)(src + row * 384 + c);
    uint4 a1 = *(const uint4*)(src + row * 384 + c + 8);
    uint4 b0 = *(const uint4*)(src + row * 384 + 128 + c);
    uint4 b1 = *(const uint4*)(src + row * 384 + 128 + c + 8);
    uint4 c0 = *(const uint4*)(zg + row * 128 + c);
    uint4 c1 = *(const uint4*)(zg + row * 128 + c + 8);
    *(uint4*)&q_s[row * 136 + c] = a0; *(uint4*)&q_s[row * 136 + c + 8] = a1;
    *(uint4*)&k_s[row * 136 + c] = b0; *(uint4*)&k_s[row * 136 + c + 8] = b1;
    *(uint4*)&z_s[row * 136 + c] = c0; *(uint4*)&z_s[row * 136 + c + 8] = c1;
  }
  __syncthreads();

  // per-wave d-slice grams
  {
    f32x16 g1, g2;
#pragma unroll
    for (int r = 0; r < 16; ++r) { g1[r] = 0.f; g2[r] = 0.f; }
#pragma unroll
    for (int ks = 0; ks < 2; ++ks) {
      const int off = w * 32 + ks * 16 + hi * 8;
      bf16x8 aq = *(const bf16x8*)&q_s[l31 * 136 + off];
      bf16x8 bk = *(const bf16x8*)&k_s[l31 * 136 + off];
      bf16x8 bz = *(const bf16x8*)&z_s[l31 * 136 + off];
      g1 = __builtin_amdgcn_mfma_f32_32x32x16_bf16(aq, bk, g1, 0, 0, 0);
      g2 = __builtin_amdgcn_mfma_f32_32x32x16_bf16(aq, bz, g2, 0, 0, 0);
    }
    const float aj = alib[l31];
#pragma unroll
    for (int r = 0; r < 16; ++r) {
      const int row = (r & 3) + 8 * (r >> 2) + 4 * hi;
      part[w][row][l31] = 0.0078125f * g1[r] + aj * g2[r];
    }
  }
  __syncthreads();

  // wave-parallel softmax, reading the 4 wave-partials directly
  const int i = t >> 3;
  const int j0 = (t & 7) * 4;
  float wv[4];
#pragma unroll
  for (int jj = 0; jj < 4; ++jj)
    wv[jj] = part[0][i][j0 + jj] + part[1][i][j0 + jj]
           + part[2][i][j0 + jj] + part[3][i][j0 + jj];
  float vmax = fmaxf(fmaxf(wv[0], wv[1]), fmaxf(wv[2], wv[3]));
  vmax = fmaxf(vmax, __shfl_xor(vmax, 1));
  vmax = fmaxf(vmax, __shfl_xor(vmax, 2));
  vmax = fmaxf(vmax, __shfl_xor(vmax, 4));
  float ssum = 0.f;
#pragma unroll
  for (int jj = 0; jj < 4; ++jj) { wv[jj] = __expf(wv[jj] - vmax); ssum += wv[jj]; }
#pragma unroll
  for (int jj = 0; jj < 4; ++jj) pbf[i * 34 + j0 + jj] = f2bf(wv[jj]);
  ssum += __shfl_xor(ssum, 1);
  ssum += __shfl_xor(ssum, 2);
  ssum += __shfl_xor(ssum, 4);
  if ((t & 7) == 0) pden[i] = 1.0f / (ssum + 1e-8f);
  __syncthreads();

  // PV via MFMA: wave w -> d-slice w*32..w*32+31
  {
    f32x16 cacc;
#pragma unroll
    for (int r = 0; r < 16; ++r) cacc[r] = 0.f;
    bf16x8 pa[2], vb[2];
#pragma unroll
    for (int ks = 0; ks < 2; ++ks) {
      bf16x8 p8, v8;
#pragma unroll
      for (int jj = 0; jj < 8; ++jj) {
        const int k = ks * 16 + hi * 8 + jj;
        p8[jj] = u2bf(pbf[l31 * 34 + k]);
        v8[jj] = u2bf(v_s[k * 128 + w * 32 + l31]);
      }
      pa[ks] = p8; vb[ks] = v8;
    }
    cacc = __builtin_amdgcn_mfma_f32_32x32x16_bf16(pa[0], vb[0], cacc, 0, 0, 0);
    cacc = __builtin_amdgcn_mfma_f32_32x32x16_bf16(pa[1], vb[1], cacc, 0, 0, 0);

    unsigned short* cb = ctx + ((long)b * S_ + s) * H_ + w * 32 + l31;
#pragma unroll
    for (int r = 0; r < 16; ++r) {
      const int row = (r & 3) + 8 * (r >> 2) + 4 * hi;
      cb[row * HD_] = f2bf(cacc[r] * pden[row]);
    }
  }
}

// -----------------------------------------------------------------------------
extern "C" void kernel_launch(void* const* d_in, const int* in_sizes, int n_in,
                              void* d_out, int out_size, void* d_ws, size_t ws_size,
                              hipStream_t stream)
{
  (void)in_sizes; (void)n_in; (void)out_size; (void)ws_size;
  const float* hidden   = (const float*)d_in[0];
  const float* residual = (const float*)d_in[1];
  const float* alibi    = (const float*)d_in[2];
  const float* Wqkv     = (const float*)d_in[4];
  const float* bqkv     = (const float*)d_in[5];
  const float* Wd       = (const float*)d_in[6];
  const float* bd       = (const float*)d_in[7];
  float* out = (float*)d_out;

  char* ws = (char*)d_ws;
  size_t off = 0;
  auto carve = [&](size_t bytes) -> void* {
    void* p = ws + off;
    off += (bytes + 255) & ~(size_t)255;
    return p;
  };
  const long nHid = (long)B_ * S_ * H_;
  const long nWq  = (long)H3_ * H_;
  unsigned short* hid_bf   = (unsigned short*)carve((size_t)nHid * 2);
  unsigned short* wqkv_bf  = (unsigned short*)carve((size_t)nWq * 2);
  unsigned short* wd_bf    = (unsigned short*)carve((size_t)H_ * H_ * 2);
  unsigned short* fused_bf = (unsigned short*)carve((size_t)B_ * S_ * H3_ * 2);
  unsigned short* z_bf     = (unsigned short*)carve((size_t)nHid * 2);
  unsigned short* ctx_bf   = (unsigned short*)carve((size_t)nHid * 2);
  float*          Gpart    = (float*)carve((size_t)64 * GP_ * 16384 * 4);
  unsigned short* ginv_bf  = (unsigned short*)carve((size_t)64 * 16384 * 2);

  // 1) bf16 casts (single launch, 3 segments)
  cvt3<<<2048, 256, 0, stream>>>(hidden, hid_bf, nHid,
                                 Wqkv, wqkv_bf, nWq,
                                 Wd, wd_bf, (long)H_ * H_);

  // 2) fused = hidden @ Wqkv^T + b_qkv  (bf16 out)
  gemm256<0><<<dim3(H3_ / 256, (B_ * S_) / 256, 1), 1024, 0, stream>>>(
      hid_bf, wqkv_bf, fused_bf, bqkv, nullptr, H_, H_, H3_, H_);

  // 3) G partials via MFMA -> Ginv via register Gauss-Jordan (sums partials)
  compute_g<<<dim3(64, GP_), 256, 0, stream>>>(fused_bf, Gpart);
  invert_g<<<64, 1024, 0, stream>>>(Gpart, ginv_bf);

  // 4) Z[b,s,n,:] = Ginv_{b,n} q_{b,n}(s)  (single-stage batched GEMM)
  zgemm<<<dim3(1, S_ / 128, 64), 256, 0, stream>>>(fused_bf, ginv_bf, z_bf);

  // 5) per-position 32x32 head attention -> ctx (bf16)
  attn_pos<<<dim3(S_, B_), 256, 0, stream>>>(fused_bf, z_bf, alibi, ctx_bf);

  // 6) out = ctx @ Wd^T + b_dense + residual  (f32 out)
  gemm256<1><<<dim3(H_ / 256, (B_ * S_) / 256, 1), 1024, 0, stream>>>(
      ctx_bf, wd_bf, out, bd, residual, H_, H_, H_, H_);
}